// Round 1
// baseline (87.309 us; speedup 1.0000x reference)
//
#include <hip/hip_runtime.h>

// LengthRegulator: expand x[B,T,D] by integer durations into out[B,MAX_LEN,D],
// plus mel_len[B] = cumsum(duration)[:, -1].
// B=32, T=512, D=512, MAX_LEN=4096, durations in [0,10).

#define B_      32
#define T_      512
#define D_      512
#define MAXLEN_ 4096

// ---------------------------------------------------------------------------
// Kernel 1: per-batch inclusive cumsum of duration (T=512), one block/batch.
// Writes cum[b][t] to workspace and mel_len[b] (as float) to the d_out tail.
// ---------------------------------------------------------------------------
__global__ void lr_cumsum_kernel(const int* __restrict__ dur,
                                 int* __restrict__ cum,
                                 float* __restrict__ mel_out) {
    const int b = blockIdx.x;
    const int t = threadIdx.x;
    __shared__ int s[T_];
    s[t] = dur[b * T_ + t];
    __syncthreads();
    // Hillis-Steele inclusive scan
    #pragma unroll
    for (int off = 1; off < T_; off <<= 1) {
        int v = (t >= off) ? s[t - off] : 0;
        __syncthreads();
        s[t] += v;
        __syncthreads();
    }
    cum[b * T_ + t] = s[t];
    if (t == T_ - 1) mel_out[b] = (float)s[t];
}

// ---------------------------------------------------------------------------
// Kernel 2: fill out[b][f][:]. 256 threads/block = 2 frame-rows, 128 threads
// per row, one float4 (16B) per thread. Binary search cum for the source
// token (searchsorted side='right' == first idx with cum[idx] > f).
// Frames f >= mel_len are zeroed (mask in the reference).
// Every output element is written -> no stale-buffer hazards.
// ---------------------------------------------------------------------------
__global__ void lr_regulate_kernel(const float* __restrict__ x,
                                   const int* __restrict__ cum,
                                   float* __restrict__ out) {
    const int gid   = blockIdx.x;
    const int b     = gid / (MAXLEN_ / 2);
    const int fbase = (gid % (MAXLEN_ / 2)) * 2;
    const int sub   = threadIdx.x >> 7;    // wave-uniform (wave 0,1 -> 0; 2,3 -> 1)
    const int lane  = threadIdx.x & 127;
    const int f     = fbase + sub;

    const int* c   = cum + b * T_;
    const int  mel = c[T_ - 1];

    float4 val = make_float4(0.f, 0.f, 0.f, 0.f);
    if (f < mel) {
        // first idx with c[idx] > f  (guaranteed < T since f < mel = c[T-1])
        int lo = 0, hi = T_;
        while (lo < hi) {
            int mid = (lo + hi) >> 1;
            if (c[mid] <= f) lo = mid + 1; else hi = mid;
        }
        const float4* src = (const float4*)(x + ((size_t)b * T_ + lo) * D_);
        val = src[lane];
    }
    float4* dst = (float4*)(out + ((size_t)b * MAXLEN_ + f) * D_);
    dst[lane] = val;
}

extern "C" void kernel_launch(void* const* d_in, const int* in_sizes, int n_in,
                              void* d_out, int out_size, void* d_ws, size_t ws_size,
                              hipStream_t stream) {
    const float* x   = (const float*)d_in[0];
    const int*   dur = (const int*)d_in[1];
    // d_in[2] is max_len (=4096), known at compile time.

    float* out     = (float*)d_out;
    float* mel_out = out + (size_t)B_ * MAXLEN_ * D_;   // tail: 32 elements
    int*   cum     = (int*)d_ws;                        // 32*512*4 = 64 KB

    lr_cumsum_kernel<<<B_, T_, 0, stream>>>(dur, cum, mel_out);
    lr_regulate_kernel<<<B_ * (MAXLEN_ / 2), 256, 0, stream>>>(x, cum, out);
}

// Round 3
// 60.034 us; speedup vs baseline: 1.4543x; 1.4543x over previous
//
#include <hip/hip_runtime.h>

// LengthRegulator: expand x[B,T,D] by integer durations into out[B,MAX_LEN,D],
// plus mel_len[B] = cumsum(duration)[:, -1].
// B=32, T=512, D=512, MAX_LEN=4096, durations in [0,10).
//
// R2: token-major scatter (read each x row ONCE, write duration copies)
// instead of frame-major gather with per-frame binary search. Zero-fill of
// masked frames [mel, MAX_LEN) is a second disjoint partition of the same
// grid. Nontemporal stores via clang ext-vector float4 (HIP_vector_type
// float4 is rejected by __builtin_nontemporal_store).

typedef float f32x4 __attribute__((ext_vector_type(4)));

#define B_      32
#define T_      512
#define D_      512
#define MAXLEN_ 4096
#define ZFR_    8                      // frames per zero-fill block
#define NEXP_   (B_ * T_)              // expand blocks
#define NZERO_  (B_ * (MAXLEN_ / ZFR_))// zero-fill blocks

// ---------------------------------------------------------------------------
// Kernel 1: per-batch inclusive cumsum of duration (T=512), one block/batch.
// Writes cum[b][t] to workspace and mel_len[b] (as float) to the d_out tail.
// ---------------------------------------------------------------------------
__global__ void lr_cumsum_kernel(const int* __restrict__ dur,
                                 int* __restrict__ cum,
                                 float* __restrict__ mel_out) {
    const int b = blockIdx.x;
    const int t = threadIdx.x;
    __shared__ int s[T_];
    s[t] = dur[b * T_ + t];
    __syncthreads();
    #pragma unroll
    for (int off = 1; off < T_; off <<= 1) {
        int v = (t >= off) ? s[t - off] : 0;
        __syncthreads();
        s[t] += v;
        __syncthreads();
    }
    cum[b * T_ + t] = s[t];
    if (t == T_ - 1) mel_out[b] = (float)s[t];
}

// ---------------------------------------------------------------------------
// Kernel 2, partition A (blocks [0, NEXP_)): one block per (b, t) token.
// 128 threads load the 2 KB source row (1 float4/lane) and store it to
// frames [cum[t-1], cum[t]) — disjoint across tokens, covers [0, mel).
// Partition B (blocks [NEXP_, NEXP_+NZERO_)): zero frames >= mel.
// Disjoint from partition A, so concurrent execution is race-free.
// Every out element is written every call -> no stale-buffer hazards.
// ---------------------------------------------------------------------------
__global__ void lr_scatter_kernel(const float* __restrict__ x,
                                  const int* __restrict__ cum,
                                  float* __restrict__ out) {
    const int gid  = blockIdx.x;
    const int lane = threadIdx.x;            // 0..127

    if (gid < NEXP_) {
        // ---- expand partition ----
        const int b = gid >> 9;              // / T_
        const int t = gid & (T_ - 1);
        const int* c  = cum + b * T_;
        const int  hi = c[t];
        const int  lo = (t == 0) ? 0 : c[t - 1];
        const int  dur = hi - lo;
        if (dur == 0) return;
        const f32x4 v =
            ((const f32x4*)(x + ((size_t)b * T_ + t) * D_))[lane];
        f32x4* dst =
            (f32x4*)(out + ((size_t)b * MAXLEN_ + lo) * D_) + lane;
        for (int i = 0; i < dur; ++i)
            __builtin_nontemporal_store(v, dst + i * (D_ / 4));
    } else {
        // ---- zero-fill partition ----
        const int zid = gid - NEXP_;
        const int b   = zid >> 9;            // / (MAXLEN_/ZFR_)
        const int f0  = (zid & (MAXLEN_ / ZFR_ - 1)) * ZFR_;
        const int mel = cum[b * T_ + T_ - 1];
        if (f0 + ZFR_ <= mel) return;        // fully inside active region
        const f32x4 z = {0.f, 0.f, 0.f, 0.f};
        f32x4* base =
            (f32x4*)(out + ((size_t)b * MAXLEN_ + f0) * D_) + lane;
        #pragma unroll
        for (int i = 0; i < ZFR_; ++i)
            if (f0 + i >= mel)
                __builtin_nontemporal_store(z, base + i * (D_ / 4));
    }
}

extern "C" void kernel_launch(void* const* d_in, const int* in_sizes, int n_in,
                              void* d_out, int out_size, void* d_ws, size_t ws_size,
                              hipStream_t stream) {
    const float* x   = (const float*)d_in[0];
    const int*   dur = (const int*)d_in[1];
    // d_in[2] is max_len (=4096), compile-time constant here.

    float* out     = (float*)d_out;
    float* mel_out = out + (size_t)B_ * MAXLEN_ * D_;   // tail: 32 elements
    int*   cum     = (int*)d_ws;                        // 32*512*4 = 64 KB

    lr_cumsum_kernel<<<B_, T_, 0, stream>>>(dur, cum, mel_out);
    lr_scatter_kernel<<<NEXP_ + NZERO_, 128, 0, stream>>>(x, cum, out);
}

// Round 4
// 59.817 us; speedup vs baseline: 1.4596x; 1.0036x over previous
//
#include <hip/hip_runtime.h>

// LengthRegulator: expand x[B,T,D] by integer durations into out[B,MAX_LEN,D],
// plus mel_len[B] = cumsum(duration)[:, -1].
// B=32, T=512, D=512, MAX_LEN=4096, durations in [0,10).
//
// R3: same token-major scatter as R2; cumsum rewritten as a barrier-free
// single-wave scan per batch (64 lanes x 8 ints, in-lane serial scan +
// __shfl_up ladder) -- the R2 version had 18 __syncthreads at 512 threads
// across only 32 blocks (pure latency, ~4-6 us).

typedef float f32x4 __attribute__((ext_vector_type(4)));
typedef int   i32x4 __attribute__((ext_vector_type(4)));

#define B_      32
#define T_      512
#define D_      512
#define MAXLEN_ 4096
#define ZFR_    8                      // frames per zero-fill block
#define NEXP_   (B_ * T_)              // expand blocks
#define NZERO_  (B_ * (MAXLEN_ / ZFR_))// zero-fill blocks

// ---------------------------------------------------------------------------
// Kernel 1: per-batch inclusive cumsum of duration (T=512).
// One wave (64 lanes) per batch; lane l owns ints [8l, 8l+8).
// No LDS, no barriers: serial scan in-lane, then shfl_up exclusive scan of
// lane totals. Writes cum to ws and mel_len (float) to the d_out tail.
// ---------------------------------------------------------------------------
__global__ void lr_cumsum_kernel(const int* __restrict__ dur,
                                 int* __restrict__ cum,
                                 float* __restrict__ mel_out) {
    const int b    = blockIdx.x;
    const int lane = threadIdx.x;          // 0..63
    const i32x4* src = (const i32x4*)(dur + b * T_);
    i32x4 a = src[lane * 2];
    i32x4 c = src[lane * 2 + 1];
    int v0 = a.x;
    int v1 = v0 + a.y;
    int v2 = v1 + a.z;
    int v3 = v2 + a.w;
    int v4 = v3 + c.x;
    int v5 = v4 + c.y;
    int v6 = v5 + c.z;
    int v7 = v6 + c.w;                     // lane-local inclusive totals
    // inclusive wave scan of per-lane totals
    int s = v7;
    #pragma unroll
    for (int d = 1; d < 64; d <<= 1) {
        int u = __shfl_up(s, d, 64);
        if (lane >= d) s += u;
    }
    const int off = s - v7;                // exclusive prefix for this lane
    i32x4 r0 = {v0 + off, v1 + off, v2 + off, v3 + off};
    i32x4 r1 = {v4 + off, v5 + off, v6 + off, v7 + off};
    i32x4* dst = (i32x4*)(cum + b * T_);
    dst[lane * 2]     = r0;
    dst[lane * 2 + 1] = r1;
    if (lane == 63) mel_out[b] = (float)(v7 + off);
}

// ---------------------------------------------------------------------------
// Kernel 2, partition A (blocks [0, NEXP_)): one block per (b, t) token.
// 128 threads load the 2 KB source row (1 float4/lane) and store it to
// frames [cum[t-1], cum[t]) — disjoint across tokens, covers [0, mel).
// Partition B (blocks [NEXP_, NEXP_+NZERO_)): zero frames >= mel.
// Disjoint from partition A, so concurrent execution is race-free.
// Every out element is written every call -> no stale-buffer hazards.
// ---------------------------------------------------------------------------
__global__ void lr_scatter_kernel(const float* __restrict__ x,
                                  const int* __restrict__ cum,
                                  float* __restrict__ out) {
    const int gid  = blockIdx.x;
    const int lane = threadIdx.x;            // 0..127

    if (gid < NEXP_) {
        // ---- expand partition ----
        const int b = gid >> 9;              // / T_
        const int t = gid & (T_ - 1);
        const int* c  = cum + b * T_;
        const int  hi = c[t];
        const int  lo = (t == 0) ? 0 : c[t - 1];
        const int  dur = hi - lo;
        if (dur == 0) return;
        const f32x4 v =
            ((const f32x4*)(x + ((size_t)b * T_ + t) * D_))[lane];
        f32x4* dst =
            (f32x4*)(out + ((size_t)b * MAXLEN_ + lo) * D_) + lane;
        for (int i = 0; i < dur; ++i)
            __builtin_nontemporal_store(v, dst + i * (D_ / 4));
    } else {
        // ---- zero-fill partition ----
        const int zid = gid - NEXP_;
        const int b   = zid >> 9;            // / (MAXLEN_/ZFR_)
        const int f0  = (zid & (MAXLEN_ / ZFR_ - 1)) * ZFR_;
        const int mel = cum[b * T_ + T_ - 1];
        if (f0 + ZFR_ <= mel) return;        // fully inside active region
        const f32x4 z = {0.f, 0.f, 0.f, 0.f};
        f32x4* base =
            (f32x4*)(out + ((size_t)b * MAXLEN_ + f0) * D_) + lane;
        #pragma unroll
        for (int i = 0; i < ZFR_; ++i)
            if (f0 + i >= mel)
                __builtin_nontemporal_store(z, base + i * (D_ / 4));
    }
}

extern "C" void kernel_launch(void* const* d_in, const int* in_sizes, int n_in,
                              void* d_out, int out_size, void* d_ws, size_t ws_size,
                              hipStream_t stream) {
    const float* x   = (const float*)d_in[0];
    const int*   dur = (const int*)d_in[1];
    // d_in[2] is max_len (=4096), compile-time constant here.

    float* out     = (float*)d_out;
    float* mel_out = out + (size_t)B_ * MAXLEN_ * D_;   // tail: 32 elements
    int*   cum     = (int*)d_ws;                        // 32*512*4 = 64 KB

    lr_cumsum_kernel<<<B_, 64, 0, stream>>>(dur, cum, mel_out);
    lr_scatter_kernel<<<NEXP_ + NZERO_, 128, 0, stream>>>(x, cum, out);
}

// Round 5
// 54.479 us; speedup vs baseline: 1.6026x; 1.0980x over previous
//
#include <hip/hip_runtime.h>

// LengthRegulator: expand x[B,T,D] by integer durations into out[B,MAX_LEN,D],
// plus mel_len[B] = cumsum(duration)[:, -1].
// B=32, T=512, D=512, MAX_LEN=4096, durations in [0,10).
//
// R4: FULLY FUSED single kernel. One 256-thread block per 2 tokens.
// Each wave redundantly computes the inclusive wave-scan of its batch's
// 512 durations in registers (8 ints/lane + shfl_up ladder; dur is 64 KB,
// L2-resident, so redundant loads are cheap), then extracts cum[t-1],
// cum[t], mel via uniform register-select + shfl. The block expands its
// token AND zero-fills its share of frames [mel, MAX_LEN) (f = mel+t+512k,
// a disjoint exact cover). No second kernel, no graph dependency, no ws.

typedef float f32x4 __attribute__((ext_vector_type(4)));
typedef int   i32x4 __attribute__((ext_vector_type(4)));

#define B_      32
#define T_      512
#define D_      512
#define MAXLEN_ 4096
#define TPB_    2                        // tokens per block
#define NBLK_   (B_ * T_ / TPB_)         // 8192 blocks, 256 threads

__global__ void lr_fused_kernel(const float* __restrict__ x,
                                const int* __restrict__ dur,
                                float* __restrict__ out,
                                float* __restrict__ mel_out) {
    const int gid  = blockIdx.x;
    const int b    = gid >> 8;               // / (T_/TPB_) = 256
    const int t0   = (gid & 255) * TPB_;
    const int sub  = threadIdx.x >> 7;       // which token of the pair
    const int half = (threadIdx.x >> 6) & 1; // which wave within the 128-group
    const int lane = threadIdx.x & 63;
    const int t    = t0 + sub;               // wave-uniform

    // ---- wave-redundant inclusive scan of duration[b][:] in registers ----
    const i32x4* src = (const i32x4*)(dur + b * T_);
    i32x4 a = src[lane * 2];
    i32x4 c = src[lane * 2 + 1];
    int v0 = a.x,      v1 = v0 + a.y, v2 = v1 + a.z, v3 = v2 + a.w;
    int v4 = v3 + c.x, v5 = v4 + c.y, v6 = v5 + c.z, v7 = v6 + c.w;
    int s = v7;
    #pragma unroll
    for (int d = 1; d < 64; d <<= 1) {
        int u = __shfl_up(s, d, 64);
        if (lane >= d) s += u;
    }
    const int off = s - v7;                  // exclusive prefix of this lane
    v0 += off; v1 += off; v2 += off; v3 += off;
    v4 += off; v5 += off; v6 += off; v7 += off;
    // lane l holds cum[8l .. 8l+7] in v0..v7

    const int mel = __shfl(v7, 63, 64);

    // ---- extract hi = cum[t], lo = cum[t-1] (t is wave-uniform) ----
    int e = t & 7;
    int sel = v0;
    sel = (e == 1) ? v1 : sel;  sel = (e == 2) ? v2 : sel;
    sel = (e == 3) ? v3 : sel;  sel = (e == 4) ? v4 : sel;
    sel = (e == 5) ? v5 : sel;  sel = (e == 6) ? v6 : sel;
    sel = (e == 7) ? v7 : sel;
    const int hi = __shfl(sel, t >> 3, 64);
    int lo = 0;
    if (t > 0) {
        int e2 = (t - 1) & 7;
        int sl = v0;
        sl = (e2 == 1) ? v1 : sl;  sl = (e2 == 2) ? v2 : sl;
        sl = (e2 == 3) ? v3 : sl;  sl = (e2 == 4) ? v4 : sl;
        sl = (e2 == 5) ? v5 : sl;  sl = (e2 == 6) ? v6 : sl;
        sl = (e2 == 7) ? v7 : sl;
        lo = __shfl(sl, (t - 1) >> 3, 64);
    }

    // ---- expand: write x[b][t] to frames [lo, hi) ----
    const int fl = half * 64 + lane;         // float4 index in row, 0..127
    const int du = hi - lo;
    if (du > 0) {
        const f32x4 v = ((const f32x4*)(x + ((size_t)b * T_ + t) * D_))[fl];
        f32x4* dst = (f32x4*)(out + ((size_t)b * MAXLEN_ + lo) * D_) + fl;
        for (int i = 0; i < du; ++i)
            __builtin_nontemporal_store(v, dst + i * (D_ / 4));
    }

    // ---- zero-fill share: frames mel + t + 512k (exact disjoint cover) ----
    const f32x4 z = {0.f, 0.f, 0.f, 0.f};
    for (int f = mel + t; f < MAXLEN_; f += T_) {
        f32x4* dz = (f32x4*)(out + ((size_t)b * MAXLEN_ + f) * D_) + fl;
        __builtin_nontemporal_store(z, dz);
    }

    if (t == 0 && threadIdx.x == 0) mel_out[b] = (float)mel;
}

extern "C" void kernel_launch(void* const* d_in, const int* in_sizes, int n_in,
                              void* d_out, int out_size, void* d_ws, size_t ws_size,
                              hipStream_t stream) {
    const float* x   = (const float*)d_in[0];
    const int*   dur = (const int*)d_in[1];
    // d_in[2] is max_len (=4096), compile-time constant here.

    float* out     = (float*)d_out;
    float* mel_out = out + (size_t)B_ * MAXLEN_ * D_;   // tail: 32 elements

    lr_fused_kernel<<<NBLK_, 256, 0, stream>>>(x, dur, out, mel_out);
}